// Round 1
// 392.607 us; speedup vs baseline: 1.0517x; 1.0517x over previous
//
#include <hip/hip_runtime.h>
#include <hip/hip_fp16.h>

// LightGCN 3-layer propagation, pull-based CSR, fp16 ego intermediates.
// Round 8: kill the fp32 acc running-sum (was 192 MB of streaming RMW
// traffic across the 3 gathers). Layers 1-2 now write only nego (fp16);
// layer 3's epilogue reads ego0/ego1/ego2 rows and writes
// acc = (e0+e1+e2+s)/4 once. ego intermediates switch bf16->fp16
// (+3 mantissa bits, values bounded << 65504) so storing ego1/ego2
// rounded instead of accumulating unrounded fp32 is a net accuracy WIN.
// Third ego buffer aliases the dead bpair region (ws 70.6 -> 74.2 MB).

#define NUM_USERS 100000
#define NUM_ITEMS 50000
#define EMB_DIM   64
#define N_EDGES   2000000
#define N_NODES   (NUM_USERS + NUM_ITEMS)          // 150000
#define NODE_FLOATS (N_NODES * EMB_DIM)            // 9,600,000
#define NODE_F4     (NODE_FLOATS / 4)              // 2,400,000

#define NBUCKET  512
#define NPB      293        // nodes per bucket; 512*293 = 150016 >= 150000
#define NPART    8          // reservation partitions (XCD heuristic)
#define NCNT     (NBUCKET * NPART)                  // 4096
#define BT       512        // threads in bucket passes
#define VPT      8          // edges per thread in bucket passes
#define TILE     (BT * VPT)                         // 4096
#define NTILE    ((N_EDGES + TILE - 1) / TILE)      // 489

typedef unsigned int uint;
typedef unsigned short ushort;
typedef unsigned long long u64;

__device__ __forceinline__ float2 h2f2(uint u) {
    __half2 h = *reinterpret_cast<const __half2*>(&u);
    return __half22float2(h);
}
__device__ __forceinline__ uint f2h2(float a, float b) {
    __half2 h = __floats2half2_rn(a, b);
    return *reinterpret_cast<uint*>(&h);
}

// ---------- init: egoA(fp16) = concat(user,item) ----------
__global__ void lgcn_init(const float4* __restrict__ user,
                          const float4* __restrict__ item,
                          uint2* __restrict__ egoA) {
    const int n_user4 = NUM_USERS * EMB_DIM / 4;
    for (int i = blockIdx.x * blockDim.x + threadIdx.x; i < NODE_F4;
         i += gridDim.x * blockDim.x) {
        float4 v = (i < n_user4) ? user[i] : item[i - n_user4];
        egoA[i] = make_uint2(f2h2(v.x, v.y), f2h2(v.z, v.w));
    }
}

__global__ void zero_ints(int* __restrict__ p, int n) {
    int i = blockIdx.x * blockDim.x + threadIdx.x;
    if (i < n) p[i] = 0;
}

// ---------- pass A: histogram into (bucket, partition) counters ----------
__global__ __launch_bounds__(BT) void bucket_hist(const int* __restrict__ src,
                                                  int* __restrict__ bucketCount) {
    __shared__ int cnt[NBUCKET];
    int t = threadIdx.x;
    int part = blockIdx.x & (NPART - 1);
    cnt[t] = 0;
    __syncthreads();
    int base = blockIdx.x * TILE + t;
    #pragma unroll
    for (int k = 0; k < VPT; ++k) {
        int e = base + k * BT;
        if (e < N_EDGES) atomicAdd(&cnt[src[e] / NPB], 1);
    }
    __syncthreads();
    int c = cnt[t];
    if (c) atomicAdd(&bucketCount[t * NPART + part], c);
}

// ---------- scan over 4096 (bucket,part) counters (1 block, 1024 thr) ----------
__global__ __launch_bounds__(1024) void bucket_scan(const int* __restrict__ bucketCount,
                                                    int* __restrict__ bucketOffset,
                                                    int* __restrict__ gCur,
                                                    int* __restrict__ rowPtr) {
    __shared__ int s[1024];
    int t = threadIdx.x;
    int4 c = *(const int4*)(bucketCount + t * 4);
    int sum = c.x + c.y + c.z + c.w;
    s[t] = sum;
    __syncthreads();
    for (int off = 1; off < 1024; off <<= 1) {
        int x = (t >= off) ? s[t - off] : 0;
        __syncthreads();
        s[t] += x;
        __syncthreads();
    }
    int base = s[t] - sum;   // exclusive
    int i0 = t * 4;
    bucketOffset[i0]     = base;
    bucketOffset[i0 + 1] = base + c.x;
    bucketOffset[i0 + 2] = base + c.x + c.y;
    bucketOffset[i0 + 3] = base + c.x + c.y + c.z;
    gCur[i0]     = base;
    gCur[i0 + 1] = base + c.x;
    gCur[i0 + 2] = base + c.x + c.y;
    gCur[i0 + 3] = base + c.x + c.y + c.z;
    if (t == 0) {
        bucketOffset[NCNT] = N_EDGES;
        rowPtr[N_NODES] = N_EDGES;
    }
}

// ---------- pass B: scatter packed edges into (bucket,part) runs ----------
// packed u64: [norm:32][src_local:9][dst:18]
__global__ __launch_bounds__(BT) void bucket_scatter(const int* __restrict__ src,
                                                     const int* __restrict__ dst,
                                                     const float* __restrict__ norm,
                                                     int* __restrict__ gCur,
                                                     u64* __restrict__ bpair) {
    __shared__ int cnt[NBUCKET];
    __shared__ int bbase[NBUCKET];
    int t = threadIdx.x;
    int part = blockIdx.x & (NPART - 1);
    cnt[t] = 0;
    __syncthreads();
    int base = blockIdx.x * TILE + t;
    #pragma unroll
    for (int k = 0; k < VPT; ++k) {
        int e = base + k * BT;
        if (e < N_EDGES) atomicAdd(&cnt[src[e] / NPB], 1);
    }
    __syncthreads();
    int c = cnt[t];
    bbase[t] = c ? atomicAdd(&gCur[t * NPART + part], c) : 0;
    __syncthreads();
    cnt[t] = 0;
    __syncthreads();
    #pragma unroll
    for (int k = 0; k < VPT; ++k) {
        int e = base + k * BT;
        if (e < N_EDGES) {
            int s = src[e];
            int b = s / NPB;
            int sl = s - b * NPB;                    // 0..292
            int r = atomicAdd(&cnt[b], 1);
            uint lo = (uint)dst[e] | ((uint)sl << 18);
            u64 packed = (u64)lo | ((u64)(uint)__float_as_uint(norm[e]) << 32);
            bpair[bbase[b] + r] = packed;
        }
    }
}

// ---------- pass C: per-bucket CSR finalize (counting sort by src_local) ----------
__global__ __launch_bounds__(1024) void csr_finalize(const int* __restrict__ bucketOffset,
                                                     const u64* __restrict__ bpair,
                                                     int* __restrict__ rowPtr,
                                                     u64* __restrict__ pairs) {
    __shared__ int cnt[NBUCKET];
    __shared__ int cur[NBUCKET];
    int b = blockIdx.x;
    int t = threadIdx.x;          // 1024 threads
    int beg = bucketOffset[b * NPART];
    int end = bucketOffset[b * NPART + NPART];
    int nodeBase = b * NPB;

    if (t < NBUCKET) cnt[t] = 0;
    __syncthreads();
    for (int i = beg + t; i < end; i += 1024) {
        uint lo = (uint)bpair[i];
        atomicAdd(&cnt[(lo >> 18) & 0x1FF], 1);
    }
    __syncthreads();
    int v = (t < NBUCKET) ? cnt[t] : 0;
    for (int off = 1; off < NBUCKET; off <<= 1) {     // inclusive scan, 512-wide
        int x = (t >= off && t < NBUCKET) ? cnt[t - off] : 0;
        __syncthreads();
        if (t < NBUCKET) cnt[t] += x;
        __syncthreads();
    }
    if (t < NBUCKET) {
        int excl = cnt[t] - v;
        cur[t] = excl;
        int node = nodeBase + t;
        if (t < NPB && node < N_NODES) rowPtr[node] = beg + excl;
    }
    __syncthreads();
    for (int i = beg + t; i < end; i += 1024) {
        u64 p = bpair[i];
        int s = ((uint)p >> 18) & 0x1FF;
        int r = atomicAdd(&cur[s], 1);
        pairs[beg + r] = p;
    }
}

// ---------- gather: 1 node/wave, 8 lane-groups of 8, uint4 row loads ----------
// finalMode==0: nego = fp16(s)                    (no acc access)
// finalMode==1: acc  = (e0 + e1 + ego + s) * 0.25 (no nego write)
__global__ void lgcn_gather(const ushort* __restrict__ ego,
                            ushort* __restrict__ nego,
                            float* __restrict__ acc,
                            const ushort* __restrict__ e0,
                            const ushort* __restrict__ e1,
                            const int* __restrict__ rowPtr,
                            const u64* __restrict__ pairs,
                            int finalMode) {
    int node = blockIdx.x * 4 + (threadIdx.x >> 6);
    int lane = threadIdx.x & 63;
    int g    = lane >> 3;           // 8 edge streams
    int sub  = lane & 7;            // 8 fp16 per lane
    if (node >= N_NODES) return;
    int beg = rowPtr[node];
    int end = rowPtr[node + 1];

    float s0 = 0.f, s1 = 0.f, s2 = 0.f, s3 = 0.f;
    float s4 = 0.f, s5 = 0.f, s6 = 0.f, s7 = 0.f;
    for (int i = beg + g; i < end; i += 8) {
        u64 p = __builtin_nontemporal_load(&pairs[i]);
        uint lo = (uint)p;
        float w = __uint_as_float((uint)(p >> 32));
        int d = lo & 0x3FFFF;
        uint4 r = *(const uint4*)(ego + ((size_t)d << 6) + (sub << 3));
        float2 q;
        q = h2f2(r.x); s0 += w * q.x; s1 += w * q.y;
        q = h2f2(r.y); s2 += w * q.x; s3 += w * q.y;
        q = h2f2(r.z); s4 += w * q.x; s5 += w * q.y;
        q = h2f2(r.w); s6 += w * q.x; s7 += w * q.y;
    }

    // reduce 8 groups -> lanes 0-7
    s0 += __shfl_down(s0, 32); s1 += __shfl_down(s1, 32);
    s2 += __shfl_down(s2, 32); s3 += __shfl_down(s3, 32);
    s4 += __shfl_down(s4, 32); s5 += __shfl_down(s5, 32);
    s6 += __shfl_down(s6, 32); s7 += __shfl_down(s7, 32);
    s0 += __shfl_down(s0, 16); s1 += __shfl_down(s1, 16);
    s2 += __shfl_down(s2, 16); s3 += __shfl_down(s3, 16);
    s4 += __shfl_down(s4, 16); s5 += __shfl_down(s5, 16);
    s6 += __shfl_down(s6, 16); s7 += __shfl_down(s7, 16);
    s0 += __shfl_down(s0, 8);  s1 += __shfl_down(s1, 8);
    s2 += __shfl_down(s2, 8);  s3 += __shfl_down(s3, 8);
    s4 += __shfl_down(s4, 8);  s5 += __shfl_down(s5, 8);
    s6 += __shfl_down(s6, 8);  s7 += __shfl_down(s7, 8);

    if (lane < 8) {
        size_t ro = ((size_t)node << 6) + (lane << 3);   // dims lane*8..lane*8+7
        if (!finalMode) {
            uint4* np = (uint4*)(nego + ro);
            *np = make_uint4(f2h2(s0, s1), f2h2(s2, s3),
                             f2h2(s4, s5), f2h2(s6, s7));
        } else {
            uint4 z0 = *(const uint4*)(e0  + ro);
            uint4 z1 = *(const uint4*)(e1  + ro);
            uint4 z2 = *(const uint4*)(ego + ro);
            float2 a, b, c;
            float4 o0, o1;
            a = h2f2(z0.x); b = h2f2(z1.x); c = h2f2(z2.x);
            o0.x = (a.x + b.x + c.x + s0) * 0.25f;
            o0.y = (a.y + b.y + c.y + s1) * 0.25f;
            a = h2f2(z0.y); b = h2f2(z1.y); c = h2f2(z2.y);
            o0.z = (a.x + b.x + c.x + s2) * 0.25f;
            o0.w = (a.y + b.y + c.y + s3) * 0.25f;
            a = h2f2(z0.z); b = h2f2(z1.z); c = h2f2(z2.z);
            o1.x = (a.x + b.x + c.x + s4) * 0.25f;
            o1.y = (a.y + b.y + c.y + s5) * 0.25f;
            a = h2f2(z0.w); b = h2f2(z1.w); c = h2f2(z2.w);
            o1.z = (a.x + b.x + c.x + s6) * 0.25f;
            o1.w = (a.y + b.y + c.y + s7) * 0.25f;
            float4* ap = (float4*)(acc + ro);
            ap[0] = o0;
            ap[1] = o1;
        }
    }
}

extern "C" void kernel_launch(void* const* d_in, const int* in_sizes, int n_in,
                              void* d_out, int out_size, void* d_ws, size_t ws_size,
                              hipStream_t stream) {
    const float* user_emb  = (const float*)d_in[0];
    const float* item_emb  = (const float*)d_in[1];
    const float* edge_norm = (const float*)d_in[2];
    const int*   edge_src  = (const int*)d_in[3];
    const int*   edge_dst  = (const int*)d_in[4];
    float* acc = (float*)d_out;

    char* w = (char*)d_ws;
    ushort* egoA  = (ushort*)w;                      w += (size_t)NODE_FLOATS * 2;   // 19.2 MB
    ushort* egoB  = (ushort*)w;                      w += (size_t)NODE_FLOATS * 2;   // 19.2 MB
    u64*   pairs  = (u64*)w;                         w += (size_t)N_EDGES * 8;       // 16 MB
    int*   rowPtr = (int*)w;                         w += (size_t)(N_NODES + 4) * 4;
    int*   bucketCount  = (int*)w;                   w += (size_t)NCNT * 4;
    int*   bucketOffset = (int*)w;                   w += (size_t)(NCNT + 4) * 4;
    int*   gCur   = (int*)w;                         w += (size_t)NCNT * 4;
    // bpair (16 MB, dead after csr_finalize) and egoC (19.2 MB, born at
    // layer-2 gather) share the tail region: lifetimes don't overlap.
    u64*   bpair  = (u64*)w;
    ushort* egoC  = (ushort*)w;                      // w += 19.2 MB (end of ws use)

    const int T = 256;
    const int EW_BLOCKS = 2048;
    const int GATHER_BLOCKS = (N_NODES + 3) / 4;     // 37500

    lgcn_init<<<EW_BLOCKS, T, 0, stream>>>(
        (const float4*)user_emb, (const float4*)item_emb, (uint2*)egoA);

    zero_ints<<<NCNT / T, T, 0, stream>>>(bucketCount, NCNT);
    bucket_hist<<<NTILE, BT, 0, stream>>>(edge_src, bucketCount);
    bucket_scan<<<1, 1024, 0, stream>>>(bucketCount, bucketOffset, gCur, rowPtr);
    bucket_scatter<<<NTILE, BT, 0, stream>>>(edge_src, edge_dst, edge_norm,
                                             gCur, bpair);
    csr_finalize<<<NBUCKET, 1024, 0, stream>>>(bucketOffset, bpair,
                                               rowPtr, pairs);

    // Layer 1: ego0(A) -> ego1(B)             (nego only)
    lgcn_gather<<<GATHER_BLOCKS, T, 0, stream>>>(egoA, egoB, acc,
                                                 (const ushort*)0, (const ushort*)0,
                                                 rowPtr, pairs, 0);
    // Layer 2: ego1(B) -> ego2(C)             (nego only)
    lgcn_gather<<<GATHER_BLOCKS, T, 0, stream>>>(egoB, egoC, acc,
                                                 (const ushort*)0, (const ushort*)0,
                                                 rowPtr, pairs, 0);
    // Layer 3: ego2(C) -> s; acc = (A + B + C + s) / 4
    lgcn_gather<<<GATHER_BLOCKS, T, 0, stream>>>(egoC, (ushort*)0, acc,
                                                 egoA, egoB,
                                                 rowPtr, pairs, 1);
}